// Round 4
// baseline (41.237 us; speedup 1.0000x reference)
//
#include <hip/hip_runtime.h>

// Rank IGR Loss — single fused kernel: per-block sorted j-tile + suffix sums
// + binary search, last-block finalize.
//
//   pair[i,j] = pos[i] & pos[j] & (d[j] - d[i] >= 1.0f)        (exact f32)
//   l1 = sum exp(-G1*(p_i-p_j))/max(cnt,1)  (factorized e^{-G1 p_i}·e^{G1 p_j})
//   l2 likewise with iou.
//
// Block (b, ic, jc): i-strip of 1024 (4/thread) × j-tile of 64. Wave 0
// rank-sorts the j-tile by d' = pos ? d : -1e30 (ties by index) and builds
// inclusive suffix sums of w1=e^{G1 p}, w2=e^{G2 iou} in the same 64-compare
// loop. Each thread then lower_bounds (6 probes, same monotone f32 predicate
// as brute force) and adds one suffix lookup per i. Non-pos j sort to the
// front and are never reached by a lookup; non-pos i have v1=v2=0.

#define G1 3.0f
#define G2 1.0f

constexpr int B    = 16;
constexpr int N    = 2048;
constexpr int TJ   = 64;         // sorted j-tile per block
constexpr int IPT  = 4;          // i per thread
constexpr int TI   = 1024;       // i-strip per block
constexpr int ICH  = N / TI;     // 2
constexpr int JCH  = N / TJ;     // 32
constexpr int NBLK = B * ICH * JCH;  // 1024

__global__ void __launch_bounds__(256)
igr_fused_kernel(const float* __restrict__ cls, const int* __restrict__ label_cls,
                 const float* __restrict__ label_loc, const float* __restrict__ pred,
                 const float* __restrict__ tgt, const int* __restrict__ dataset_id,
                 double* __restrict__ part, unsigned* __restrict__ counter,
                 float* __restrict__ out) {
  __shared__ uint4  stile[TJ];            // {ordkey(d'), idx, w1 bits, w2 bits}
  __shared__ float  ssd[TJ];              // sorted d'
  __shared__ float  suf1[TJ + 1], suf2[TJ + 1];  // inclusive suffix sums, [TJ]=0
  __shared__ double red[3][4];
  __shared__ double bl1[B], bl2[B], bval[B];
  __shared__ unsigned s_last;

  const int bid = blockIdx.x;
  const int b   = bid >> 6;               // 64 blocks per batch
  const int r   = bid & 63;
  const int ic  = r >> 5;
  const int jc  = r & 31;
  const int t   = threadIdx.x;
  const int base = b * N;

  const float tx1 = tgt[b * 4 + 0], ty1 = tgt[b * 4 + 1];
  const float tx2 = tgt[b * 4 + 2], ty2 = tgt[b * 4 + 3];
  const float ta  = (tx2 - tx1) * (ty2 - ty1);
  const float tcx = (tx1 + tx2) * 0.5f, tcy = (ty1 + ty2) * 0.5f;

  const float* __restrict__ pb = pred      + (size_t)b * 4 * N;
  const float* __restrict__ lb = label_loc + (size_t)b * 4 * N;

  auto elem = [&](int n, float& d, float& prob, float& iou, bool& pos) {
    float x1 = pb[n], y1 = pb[N + n], x2 = pb[2 * N + n], y2 = pb[3 * N + n];
    float ww = fmaxf(fminf(tx2, x2) - fmaxf(tx1, x1), 0.f);
    float hh = fmaxf(fminf(ty2, y2) - fmaxf(ty1, y1), 0.f);
    float inter = ww * hh;
    iou  = inter / ((x2 - x1) * (y2 - y1) + ta - inter);
    prob = __expf(cls[((size_t)(base + n)) * 2 + 1]);
    pos  = label_cls[base + n] > 0;
    float cx = lb[n] + tx1, cy = lb[N + n] + ty1;
    float dx = cx - tcx, dy = cy - tcy;
    d = sqrtf(dx * dx + dy * dy);
  };

  // ---- stage j tile (wave 0) ----
  float dm_j = 0.f; unsigned uj = 0u;
  if (t < TJ) {
    float d, prob, iou; bool pos;
    elem(jc * TJ + t, d, prob, iou, pos);
    dm_j = pos ? d : -1e30f;               // !pos can never satisfy cond
    uj = __float_as_uint(dm_j);
    uj ^= (uj & 0x80000000u) ? 0xFFFFFFFFu : 0x80000000u;  // order-preserving
    stile[t] = make_uint4(uj, (unsigned)t,
                          __float_as_uint(__expf(G1 * prob)),
                          __float_as_uint(__expf(G2 * iou)));
  }
  if (t == TJ) { suf1[TJ] = 0.f; suf2[TJ] = 0.f; }

  // ---- per-thread i data (waves 1-3 overlap the sort wait) ----
  float di[IPT], v1i[IPT], v2i[IPT];
#pragma unroll
  for (int k = 0; k < IPT; ++k) {
    float d, prob, iou; bool pos;
    elem(ic * TI + k * 256 + t, d, prob, iou, pos);
    di[k]  = d;
    v1i[k] = pos ? __expf(-G1 * prob) : 0.f;   // >0 iff pos (no underflow here)
    v2i[k] = pos ? __expf(-G2 * iou)  : 0.f;
  }
  __syncthreads();

  // ---- rank-sort + inclusive suffix sums (wave 0, one 64-compare loop) ----
  if (t < TJ) {
    const unsigned long long mykey = ((unsigned long long)uj << 32) | (unsigned)t;
    int rank = 0; float s1 = 0.f, s2 = 0.f;
#pragma unroll 8
    for (int q = 0; q < TJ; ++q) {
      uint4 v = stile[q];                  // LDS broadcast
      unsigned long long kq = ((unsigned long long)v.x << 32) | v.y;
      bool lt = kq < mykey;
      rank += lt ? 1 : 0;
      s1 += lt ? 0.f : __uint_as_float(v.z);
      s2 += lt ? 0.f : __uint_as_float(v.w);
    }
    ssd[rank] = dm_j; suf1[rank] = s1; suf2[rank] = s2;   // rank is a bijection
  }
  __syncthreads();

  // ---- 4 binary searches + suffix lookups ----
  double p1 = 0.0, p2 = 0.0; int cnt = 0;
#pragma unroll
  for (int k = 0; k < IPT; ++k) {
    const float d = di[k];
    int kk = 0;
#pragma unroll
    for (int w = TJ >> 1; w > 0; w >>= 1)       // exact monotone f32 predicate
      kk += (ssd[kk + w - 1] - d >= 1.0f) ? 0 : w;
    kk += (ssd[kk] - d >= 1.0f) ? 0 : 1;        // kk in [0, TJ]
    p1 += (double)v1i[k] * (double)suf1[kk];
    p2 += (double)v2i[k] * (double)suf2[kk];
    cnt += (v1i[k] > 0.f) ? (TJ - kk) : 0;      // suffix is all pos & cond
  }
  double pc = (double)cnt;

  for (int off = 32; off; off >>= 1) {
    p1 += __shfl_down(p1, off);
    p2 += __shfl_down(p2, off);
    pc += __shfl_down(pc, off);
  }
  const int wv = t >> 6, lane = t & 63;
  if (lane == 0) { red[0][wv] = p1; red[1][wv] = p2; red[2][wv] = pc; }
  __syncthreads();
  if (t == 0) {
    part[(size_t)bid * 3 + 0] = red[0][0] + red[0][1] + red[0][2] + red[0][3];
    part[(size_t)bid * 3 + 1] = red[1][0] + red[1][1] + red[1][2] + red[1][3];
    part[(size_t)bid * 3 + 2] = red[2][0] + red[2][1] + red[2][2] + red[2][3];
    __threadfence();                             // release partials (device scope)
    unsigned old = atomicAdd(counter, 1u);
    s_last = (old == (unsigned)(NBLK - 1)) ? 1u : 0u;
  }
  __syncthreads();

  if (s_last) {                                  // true last block finalizes
    __threadfence();                             // acquire
    const int bb = t >> 4, kq = t & 15;          // 16 batches x 16 threads
    double q1 = 0, q2 = 0, qc = 0;
    const volatile double* vp = part;
#pragma unroll
    for (int q = 0; q < 4; ++q) {                // 64 partials per batch
      size_t idx = (size_t)(bb * 64 + kq + q * 16) * 3;
      q1 += vp[idx]; q2 += vp[idx + 1]; qc += vp[idx + 2];
    }
    for (int off = 8; off; off >>= 1) {
      q1 += __shfl_down(q1, off, 16);
      q2 += __shfl_down(q2, off, 16);
      qc += __shfl_down(qc, off, 16);
    }
    if (kq == 0) {
      bool valid = (dataset_id[bb] != 1) && (qc > 0.0);
      double denom = fmax(qc, 1.0);
      bl1[bb]  = valid ? q1 / denom : 0.0;
      bl2[bb]  = valid ? q2 / denom : 0.0;
      bval[bb] = valid ? 1.0 : 0.0;
    }
    __syncthreads();
    if (t == 0) {
      double nv = 0, f1 = 0, f2 = 0;
      for (int x = 0; x < B; ++x) { nv += bval[x]; f1 += bl1[x]; f2 += bl2[x]; }
      out[0] = (float)((nv > 0) ? f1 / nv : 0.0);
      out[1] = (float)((nv > 0) ? f2 / nv : 0.0);
    }
  }
}

extern "C" void kernel_launch(void* const* d_in, const int* in_sizes, int n_in,
                              void* d_out, int out_size, void* d_ws, size_t ws_size,
                              hipStream_t stream) {
  const float* cls       = (const float*)d_in[0];
  const int*   label_cls = (const int*)d_in[1];
  const float* label_loc = (const float*)d_in[2];
  const float* pred      = (const float*)d_in[3];
  const float* tgt       = (const float*)d_in[4];
  const int*   dset      = (const int*)d_in[5];

  char*     ws      = (char*)d_ws;
  unsigned* counter = (unsigned*)ws;            // zeroed each call (memsetAsync)
  double*   part    = (double*)(ws + 64);       // NBLK*3 doubles = 24 KB

  hipMemsetAsync(counter, 0, sizeof(unsigned), stream);
  igr_fused_kernel<<<NBLK, 256, 0, stream>>>(cls, label_cls, label_loc, pred,
                                             tgt, dset, part, counter,
                                             (float*)d_out);
}

// Round 5
// 16.572 us; speedup vs baseline: 2.4884x; 2.4884x over previous
//
#include <hip/hip_runtime.h>

// Rank IGR Loss — two kernels, no device-scope sync (fences/atomics cost
// ~20us on XCD-noncoherent L2 — R3/R4 lesson).
//
// K1 (1024 blocks): per-block sorted 64-elem j-tile + inclusive suffix sums
//   of w1=e^{G1 p}, w2=e^{G2 iou}; each thread binary-searches for its 4
//   i-elems with the EXACT brute-force f32 predicate (d_j - d_i >= 1.0f,
//   monotone in d_j) and accumulates suffix lookups. Non-pos j are masked to
//   d'=-1e30 (sort to front, never satisfy); non-pos i have v1=v2=0.
// K2 (1 block): reduce 64 double-triples per batch, batch-mean the valid ones.

#define G1 3.0f
#define G2 1.0f

constexpr int B    = 16;
constexpr int N    = 2048;
constexpr int TJ   = 64;         // sorted j-tile per block
constexpr int IPT  = 4;          // i per thread
constexpr int TI   = 1024;       // i-strip per block
constexpr int ICH  = N / TI;     // 2
constexpr int JCH  = N / TJ;     // 32
constexpr int PB   = ICH * JCH;  // 64 partial-triples per batch
constexpr int NBLK = B * PB;     // 1024

__global__ void __launch_bounds__(256)
pair_kernel(const float* __restrict__ cls, const int* __restrict__ label_cls,
            const float* __restrict__ label_loc, const float* __restrict__ pred,
            const float* __restrict__ tgt, double* __restrict__ part) {
  __shared__ uint4  stile[TJ];            // {ordkey(d'), idx, w1 bits, w2 bits}
  __shared__ float  ssd[TJ];              // sorted d'
  __shared__ float  suf1[TJ + 1], suf2[TJ + 1];  // inclusive suffix sums, [TJ]=0
  __shared__ double red[3][4];

  const int bid = blockIdx.x;
  const int b   = bid >> 6;               // 64 blocks per batch
  const int r   = bid & 63;
  const int ic  = r >> 5;
  const int jc  = r & 31;
  const int t   = threadIdx.x;
  const int base = b * N;

  const float tx1 = tgt[b * 4 + 0], ty1 = tgt[b * 4 + 1];
  const float tx2 = tgt[b * 4 + 2], ty2 = tgt[b * 4 + 3];
  const float ta  = (tx2 - tx1) * (ty2 - ty1);
  const float tcx = (tx1 + tx2) * 0.5f, tcy = (ty1 + ty2) * 0.5f;

  const float* __restrict__ pb = pred      + (size_t)b * 4 * N;
  const float* __restrict__ lb = label_loc + (size_t)b * 4 * N;

  auto elem = [&](int n, float& d, float& prob, float& iou, bool& pos) {
    float x1 = pb[n], y1 = pb[N + n], x2 = pb[2 * N + n], y2 = pb[3 * N + n];
    float ww = fmaxf(fminf(tx2, x2) - fmaxf(tx1, x1), 0.f);
    float hh = fmaxf(fminf(ty2, y2) - fmaxf(ty1, y1), 0.f);
    float inter = ww * hh;
    iou  = inter / ((x2 - x1) * (y2 - y1) + ta - inter);
    prob = __expf(cls[((size_t)(base + n)) * 2 + 1]);
    pos  = label_cls[base + n] > 0;
    float cx = lb[n] + tx1, cy = lb[N + n] + ty1;
    float dx = cx - tcx, dy = cy - tcy;
    d = sqrtf(dx * dx + dy * dy);
  };

  // ---- stage j tile (wave 0) ----
  float dm_j = 0.f; unsigned uj = 0u;
  if (t < TJ) {
    float d, prob, iou; bool pos;
    elem(jc * TJ + t, d, prob, iou, pos);
    dm_j = pos ? d : -1e30f;               // !pos can never satisfy cond
    uj = __float_as_uint(dm_j);
    uj ^= (uj & 0x80000000u) ? 0xFFFFFFFFu : 0x80000000u;  // order-preserving
    stile[t] = make_uint4(uj, (unsigned)t,
                          __float_as_uint(__expf(G1 * prob)),
                          __float_as_uint(__expf(G2 * iou)));
  }
  if (t == TJ) { suf1[TJ] = 0.f; suf2[TJ] = 0.f; }

  // ---- per-thread i data (waves 1-3 overlap the j staging) ----
  float di[IPT], v1i[IPT], v2i[IPT];
#pragma unroll
  for (int k = 0; k < IPT; ++k) {
    float d, prob, iou; bool pos;
    elem(ic * TI + k * 256 + t, d, prob, iou, pos);
    di[k]  = d;
    v1i[k] = pos ? __expf(-G1 * prob) : 0.f;   // >0 iff pos
    v2i[k] = pos ? __expf(-G2 * iou)  : 0.f;
  }
  __syncthreads();

  // ---- rank-sort + inclusive suffix sums (wave 0, one 64-compare loop) ----
  if (t < TJ) {
    const unsigned long long mykey = ((unsigned long long)uj << 32) | (unsigned)t;
    int rank = 0; float s1 = 0.f, s2 = 0.f;
#pragma unroll 8
    for (int q = 0; q < TJ; ++q) {
      uint4 v = stile[q];                  // LDS broadcast
      unsigned long long kq = ((unsigned long long)v.x << 32) | v.y;
      bool lt = kq < mykey;
      rank += lt ? 1 : 0;
      s1 += lt ? 0.f : __uint_as_float(v.z);
      s2 += lt ? 0.f : __uint_as_float(v.w);
    }
    ssd[rank] = dm_j; suf1[rank] = s1; suf2[rank] = s2;   // rank is a bijection
  }
  __syncthreads();

  // ---- 4 binary searches + suffix lookups ----
  double p1 = 0.0, p2 = 0.0; int cnt = 0;
#pragma unroll
  for (int k = 0; k < IPT; ++k) {
    const float d = di[k];
    int kk = 0;
#pragma unroll
    for (int w = TJ >> 1; w > 0; w >>= 1)       // exact monotone f32 predicate
      kk += (ssd[kk + w - 1] - d >= 1.0f) ? 0 : w;
    kk += (ssd[kk] - d >= 1.0f) ? 0 : 1;        // kk in [0, TJ]
    p1 += (double)v1i[k] * (double)suf1[kk];
    p2 += (double)v2i[k] * (double)suf2[kk];
    cnt += (v1i[k] > 0.f) ? (TJ - kk) : 0;      // suffix is all pos & cond
  }
  double pc = (double)cnt;

  for (int off = 32; off; off >>= 1) {
    p1 += __shfl_down(p1, off);
    p2 += __shfl_down(p2, off);
    pc += __shfl_down(pc, off);
  }
  const int wv = t >> 6, lane = t & 63;
  if (lane == 0) { red[0][wv] = p1; red[1][wv] = p2; red[2][wv] = pc; }
  __syncthreads();
  if (t == 0) {
    part[(size_t)bid * 3 + 0] = red[0][0] + red[0][1] + red[0][2] + red[0][3];
    part[(size_t)bid * 3 + 1] = red[1][0] + red[1][1] + red[1][2] + red[1][3];
    part[(size_t)bid * 3 + 2] = red[2][0] + red[2][1] + red[2][2] + red[2][3];
  }
}

__global__ void finalize_kernel(const double* __restrict__ part,
                                const int* __restrict__ dataset_id,
                                float* __restrict__ out) {
  __shared__ double sl1[B], sl2[B], sv[B];
  int t = threadIdx.x;
  int b = t >> 4, k = t & 15;             // 16 threads per batch

  double s1 = 0, s2 = 0, sc = 0;
#pragma unroll
  for (int q = 0; q < PB; q += 16) {
    size_t idx = (size_t)(b * PB + k + q) * 3;
    s1 += part[idx]; s2 += part[idx + 1]; sc += part[idx + 2];
  }
  for (int off = 8; off; off >>= 1) {
    s1 += __shfl_down(s1, off, 16);
    s2 += __shfl_down(s2, off, 16);
    sc += __shfl_down(sc, off, 16);
  }
  if (k == 0) {
    double denom = fmax(sc, 1.0);
    bool valid = (dataset_id[b] != 1) && (sc > 0.0);
    sl1[b] = valid ? s1 / denom : 0.0;
    sl2[b] = valid ? s2 / denom : 0.0;
    sv[b]  = valid ? 1.0 : 0.0;
  }
  __syncthreads();
  if (t == 0) {
    double nv = 0, f1 = 0, f2 = 0;
    for (int bb = 0; bb < B; ++bb) { nv += sv[bb]; f1 += sl1[bb]; f2 += sl2[bb]; }
    out[0] = (float)((nv > 0) ? f1 / nv : 0.0);
    out[1] = (float)((nv > 0) ? f2 / nv : 0.0);
  }
}

extern "C" void kernel_launch(void* const* d_in, const int* in_sizes, int n_in,
                              void* d_out, int out_size, void* d_ws, size_t ws_size,
                              hipStream_t stream) {
  const float* cls       = (const float*)d_in[0];
  const int*   label_cls = (const int*)d_in[1];
  const float* label_loc = (const float*)d_in[2];
  const float* pred      = (const float*)d_in[3];
  const float* tgt       = (const float*)d_in[4];
  const int*   dset      = (const int*)d_in[5];

  double* part = (double*)d_ws;           // NBLK*3 doubles = 24 KB

  pair_kernel<<<NBLK, 256, 0, stream>>>(cls, label_cls, label_loc, pred, tgt, part);
  finalize_kernel<<<1, 256, 0, stream>>>(part, dset, (float*)d_out);
}